// Round 1
// baseline (5716.427 us; speedup 1.0000x reference)
//
#include <hip/hip_runtime.h>
#include <math.h>

#define T_DIM 1024
#define B_DIM 4
#define H_DIM 1024
#define NHEAD 16
#define DHEAD 64
#define NROWS (T_DIM * B_DIM)   // 4096
#define LPOS  (2 * T_DIM - 1)   // 2047

// ---------------- LayerNorm: one block per row of [T*B, H] ----------------
__global__ __launch_bounds__(256) void ln_kernel(const float* __restrict__ x,
                                                 const float* __restrict__ w,
                                                 const float* __restrict__ b,
                                                 float* __restrict__ y) {
    int row = blockIdx.x;
    const float* xr = x + (size_t)row * H_DIM;
    float* yr = y + (size_t)row * H_DIM;
    int tid = threadIdx.x;

    float4 v = reinterpret_cast<const float4*>(xr)[tid];
    float s  = v.x + v.y + v.z + v.w;
    float sq = v.x * v.x + v.y * v.y + v.z * v.z + v.w * v.w;

    #pragma unroll
    for (int m = 32; m; m >>= 1) {
        s  += __shfl_xor(s, m);
        sq += __shfl_xor(sq, m);
    }
    __shared__ float red0[4], red1[4];
    int wave = tid >> 6, lane = tid & 63;
    if (lane == 0) { red0[wave] = s; red1[wave] = sq; }
    __syncthreads();
    float tot   = red0[0] + red0[1] + red0[2] + red0[3];
    float totsq = red1[0] + red1[1] + red1[2] + red1[3];
    float mean = tot * (1.0f / H_DIM);
    float var  = totsq * (1.0f / H_DIM) - mean * mean;
    float rstd = rsqrtf(var + 1e-5f);

    float4 wv = reinterpret_cast<const float4*>(w)[tid];
    float4 bv = reinterpret_cast<const float4*>(b)[tid];
    float4 o;
    o.x = (v.x - mean) * rstd * wv.x + bv.x;
    o.y = (v.y - mean) * rstd * wv.y + bv.y;
    o.z = (v.z - mean) * rstd * wv.z + bv.z;
    o.w = (v.w - mean) * rstd * wv.w + bv.w;
    reinterpret_cast<float4*>(yr)[tid] = o;
}

// ------------- GEMM C[M,N] = A[M,K] @ B[N,K]^T + bias (optional) -----------
// 64x64 tile, BK=16, 256 threads, 4x4 register tile per thread.
__global__ __launch_bounds__(256) void gemm_bt(const float* __restrict__ A,
                                               const float* __restrict__ Bm,
                                               const float* __restrict__ bias,
                                               float* __restrict__ C,
                                               int M, int N, int K) {
    __shared__ float As[64][17];
    __shared__ float Bs[64][17];
    int tid = threadIdx.x;
    int row0 = blockIdx.y * 64, col0 = blockIdx.x * 64;
    int tx = tid & 15, ty = tid >> 4;
    int lr = tid >> 2, lc = (tid & 3) << 2;

    float acc[4][4] = {};
    for (int k0 = 0; k0 < K; k0 += 16) {
        int ga = row0 + lr;
        float4 av = make_float4(0.f, 0.f, 0.f, 0.f);
        if (ga < M) av = *reinterpret_cast<const float4*>(&A[(size_t)ga * K + k0 + lc]);
        As[lr][lc + 0] = av.x; As[lr][lc + 1] = av.y;
        As[lr][lc + 2] = av.z; As[lr][lc + 3] = av.w;

        int gb = col0 + lr;
        float4 bv = make_float4(0.f, 0.f, 0.f, 0.f);
        if (gb < N) bv = *reinterpret_cast<const float4*>(&Bm[(size_t)gb * K + k0 + lc]);
        Bs[lr][lc + 0] = bv.x; Bs[lr][lc + 1] = bv.y;
        Bs[lr][lc + 2] = bv.z; Bs[lr][lc + 3] = bv.w;
        __syncthreads();

        #pragma unroll
        for (int k = 0; k < 16; ++k) {
            float a0 = As[ty * 4 + 0][k], a1 = As[ty * 4 + 1][k];
            float a2 = As[ty * 4 + 2][k], a3 = As[ty * 4 + 3][k];
            float b0 = Bs[tx * 4 + 0][k], b1 = Bs[tx * 4 + 1][k];
            float b2 = Bs[tx * 4 + 2][k], b3 = Bs[tx * 4 + 3][k];
            acc[0][0] += a0 * b0; acc[0][1] += a0 * b1; acc[0][2] += a0 * b2; acc[0][3] += a0 * b3;
            acc[1][0] += a1 * b0; acc[1][1] += a1 * b1; acc[1][2] += a1 * b2; acc[1][3] += a1 * b3;
            acc[2][0] += a2 * b0; acc[2][1] += a2 * b1; acc[2][2] += a2 * b2; acc[2][3] += a2 * b3;
            acc[3][0] += a3 * b0; acc[3][1] += a3 * b1; acc[3][2] += a3 * b2; acc[3][3] += a3 * b3;
        }
        __syncthreads();
    }

    #pragma unroll
    for (int ii = 0; ii < 4; ++ii) {
        int gr = row0 + ty * 4 + ii;
        if (gr >= M) continue;
        #pragma unroll
        for (int jj = 0; jj < 4; ++jj) {
            int gc = col0 + tx * 4 + jj;
            if (gc < N) {
                float o = acc[ii][jj];
                if (bias) o += bias[gc];
                C[(size_t)gr * N + gc] = o;
            }
        }
    }
}

// ------------- Attention: one block per (query i, b, head n) --------------
// score[i,j] = ((q+rwb)·k[j] + (q+rrb)·r[j-i+T-1]) * 1/sqrt(D); softmax; PV.
__global__ __launch_bounds__(256) void attn_kernel(const float* __restrict__ qkv, // [T*B, 3H]
                                                   const float* __restrict__ r,   // [2T-1, H]
                                                   const float* __restrict__ rwb, // [NH*D]
                                                   const float* __restrict__ rrb, // [NH*D]
                                                   float* __restrict__ out) {     // [T*B, H]
    int i = blockIdx.x;
    int b = blockIdx.y / NHEAD;
    int n = blockIdx.y % NHEAD;
    int tid = threadIdx.x;
    int wave = tid >> 6, lane = tid & 63;

    __shared__ float qw[DHEAD], qr[DHEAD];
    __shared__ float s[T_DIM];
    __shared__ float red[8];
    __shared__ float pv[4][DHEAD];

    if (tid < DHEAD) {
        float qv = qkv[((size_t)(i * B_DIM + b)) * (3 * H_DIM) + n * DHEAD + tid];
        qw[tid] = qv + rwb[n * DHEAD + tid];
        qr[tid] = qv + rrb[n * DHEAD + tid];
    }
    __syncthreads();

    const float scale = 0.125f;  // 1/sqrt(64)
    // Phase 1: scores (each wave handles one j per iter; coalesced loads)
    for (int j = wave; j < T_DIM; j += 4) {
        float kv = qkv[((size_t)(j * B_DIM + b)) * (3 * H_DIM) + H_DIM + n * DHEAD + lane];
        float rv = r[(size_t)(j - i + T_DIM - 1) * H_DIM + n * DHEAD + lane];
        float val = kv * qw[lane] + rv * qr[lane];
        #pragma unroll
        for (int m = 32; m; m >>= 1) val += __shfl_xor(val, m);
        if (lane == 0) s[j] = val * scale;
    }
    __syncthreads();

    // Phase 2: softmax over s[0..T)
    float lm = -INFINITY;
    for (int j = tid; j < T_DIM; j += 256) lm = fmaxf(lm, s[j]);
    #pragma unroll
    for (int m = 32; m; m >>= 1) lm = fmaxf(lm, __shfl_xor(lm, m));
    if (lane == 0) red[wave] = lm;
    __syncthreads();
    float gmax = fmaxf(fmaxf(red[0], red[1]), fmaxf(red[2], red[3]));

    float ls = 0.f;
    for (int j = tid; j < T_DIM; j += 256) {
        float e = __expf(s[j] - gmax);
        s[j] = e;
        ls += e;
    }
    #pragma unroll
    for (int m = 32; m; m >>= 1) ls += __shfl_xor(ls, m);
    if (lane == 0) red[4 + wave] = ls;
    __syncthreads();
    float inv = 1.0f / (red[4] + red[5] + red[6] + red[7]);

    // Phase 3: PV — wave w covers j in [w*256, w*256+256), lane = d
    float acc = 0.f;
    int j0 = wave * 256;
    for (int j = j0; j < j0 + 256; ++j) {
        acc += s[j] * qkv[((size_t)(j * B_DIM + b)) * (3 * H_DIM) + 2 * H_DIM + n * DHEAD + lane];
    }
    pv[wave][lane] = acc;
    __syncthreads();
    if (tid < DHEAD) {
        float o = (pv[0][tid] + pv[1][tid] + pv[2][tid] + pv[3][tid]) * inv;
        out[((size_t)(i * B_DIM + b)) * H_DIM + n * DHEAD + tid] = o;
    }
}

extern "C" void kernel_launch(void* const* d_in, const int* in_sizes, int n_in,
                              void* d_out, int out_size, void* d_ws, size_t ws_size,
                              hipStream_t stream) {
    const float* x          = (const float*)d_in[0];   // [T,B,H]
    const float* pos        = (const float*)d_in[1];   // [2T-1,1,H]
    // d_in[2] = attn_mask: all-False in this problem -> identity, skipped
    const float* ln_w       = (const float*)d_in[3];
    const float* ln_b       = (const float*)d_in[4];
    const float* in_proj_w  = (const float*)d_in[5];   // [3H,H]
    const float* in_proj_b  = (const float*)d_in[6];   // [3H]
    const float* pos_proj_w = (const float*)d_in[7];   // [H,H]
    const float* r_w_bias   = (const float*)d_in[8];   // [NH,D]
    const float* r_r_bias   = (const float*)d_in[9];   // [NH,D]
    const float* out_proj_w = (const float*)d_in[10];  // [H,H]
    const float* out_proj_b = (const float*)d_in[11];  // [H]
    float* out = (float*)d_out;

    float* qn   = (float*)d_ws;                          // [4096,1024]
    float* qkv  = qn + (size_t)NROWS * H_DIM;            // [4096,3072]
    float* rbuf = qkv + (size_t)NROWS * 3 * H_DIM;       // [2047,1024]
    float* attn_out = qn;                                // reuse qn region

    // 1. LayerNorm
    ln_kernel<<<NROWS, 256, 0, stream>>>(x, ln_w, ln_b, qn);

    // 2. qkv = qn @ in_proj_w^T + in_proj_b   [4096,3072]
    gemm_bt<<<dim3(3 * H_DIM / 64, NROWS / 64), 256, 0, stream>>>(
        qn, in_proj_w, in_proj_b, qkv, NROWS, 3 * H_DIM, H_DIM);

    // 3. r = pos @ pos_proj_w^T   [2047,1024] (no bias)
    gemm_bt<<<dim3(H_DIM / 64, (LPOS + 63) / 64), 256, 0, stream>>>(
        pos, pos_proj_w, nullptr, rbuf, LPOS, H_DIM, H_DIM);

    // 4. attention
    attn_kernel<<<dim3(T_DIM, B_DIM * NHEAD), 256, 0, stream>>>(
        qkv, rbuf, r_w_bias, r_r_bias, attn_out);

    // 5. o = attn_out @ out_proj_w^T + out_proj_b
    gemm_bt<<<dim3(H_DIM / 64, NROWS / 64), 256, 0, stream>>>(
        attn_out, out_proj_w, out_proj_b, out, NROWS, H_DIM, H_DIM);
}

// Round 2
// 939.323 us; speedup vs baseline: 6.0857x; 6.0857x over previous
//
#include <hip/hip_runtime.h>
#include <math.h>

#define T_DIM 1024
#define B_DIM 4
#define H_DIM 1024
#define NHEAD 16
#define DHEAD 64
#define NROWS (T_DIM * B_DIM)   // 4096
#define LPOS  (2 * T_DIM - 1)   // 2047

typedef __attribute__((ext_vector_type(8))) short bfrag;   // 8 bf16 (4 VGPRs)
typedef __attribute__((ext_vector_type(4))) float facc;    // 4 f32 acc

static __device__ __forceinline__ short f2bf(float f) {
    unsigned u = __builtin_bit_cast(unsigned, f);
    u = (u + 0x7FFFu + ((u >> 16) & 1u)) >> 16;   // RNE
    return (short)u;
}

// ---------------- LayerNorm: one block per row of [T*B, H] ----------------
__global__ __launch_bounds__(256) void ln_kernel(const float* __restrict__ x,
                                                 const float* __restrict__ w,
                                                 const float* __restrict__ b,
                                                 float* __restrict__ y) {
    int row = blockIdx.x;
    const float* xr = x + (size_t)row * H_DIM;
    float* yr = y + (size_t)row * H_DIM;
    int tid = threadIdx.x;

    float4 v = reinterpret_cast<const float4*>(xr)[tid];
    float s  = v.x + v.y + v.z + v.w;
    float sq = v.x * v.x + v.y * v.y + v.z * v.z + v.w * v.w;

    #pragma unroll
    for (int m = 32; m; m >>= 1) {
        s  += __shfl_xor(s, m);
        sq += __shfl_xor(sq, m);
    }
    __shared__ float red0[4], red1[4];
    int wave = tid >> 6, lane = tid & 63;
    if (lane == 0) { red0[wave] = s; red1[wave] = sq; }
    __syncthreads();
    float tot   = red0[0] + red0[1] + red0[2] + red0[3];
    float totsq = red1[0] + red1[1] + red1[2] + red1[3];
    float mean = tot * (1.0f / H_DIM);
    float var  = totsq * (1.0f / H_DIM) - mean * mean;
    float rstd = rsqrtf(var + 1e-5f);

    float4 wv = reinterpret_cast<const float4*>(w)[tid];
    float4 bv = reinterpret_cast<const float4*>(b)[tid];
    float4 o;
    o.x = (v.x - mean) * rstd * wv.x + bv.x;
    o.y = (v.y - mean) * rstd * wv.y + bv.y;
    o.z = (v.z - mean) * rstd * wv.z + bv.z;
    o.w = (v.w - mean) * rstd * wv.w + bv.w;
    reinterpret_cast<float4*>(yr)[tid] = o;
}

// ------------- GEMM C[M,N] = A[M,K] @ B[N,K]^T + bias (optional) -----------
__global__ __launch_bounds__(256) void gemm_bt(const float* __restrict__ A,
                                               const float* __restrict__ Bm,
                                               const float* __restrict__ bias,
                                               float* __restrict__ C,
                                               int M, int N, int K) {
    __shared__ float As[64][17];
    __shared__ float Bs[64][17];
    int tid = threadIdx.x;
    int row0 = blockIdx.y * 64, col0 = blockIdx.x * 64;
    int tx = tid & 15, ty = tid >> 4;
    int lr = tid >> 2, lc = (tid & 3) << 2;

    float acc[4][4] = {};
    for (int k0 = 0; k0 < K; k0 += 16) {
        int ga = row0 + lr;
        float4 av = make_float4(0.f, 0.f, 0.f, 0.f);
        if (ga < M) av = *reinterpret_cast<const float4*>(&A[(size_t)ga * K + k0 + lc]);
        As[lr][lc + 0] = av.x; As[lr][lc + 1] = av.y;
        As[lr][lc + 2] = av.z; As[lr][lc + 3] = av.w;

        int gb = col0 + lr;
        float4 bv = make_float4(0.f, 0.f, 0.f, 0.f);
        if (gb < N) bv = *reinterpret_cast<const float4*>(&Bm[(size_t)gb * K + k0 + lc]);
        Bs[lr][lc + 0] = bv.x; Bs[lr][lc + 1] = bv.y;
        Bs[lr][lc + 2] = bv.z; Bs[lr][lc + 3] = bv.w;
        __syncthreads();

        #pragma unroll
        for (int k = 0; k < 16; ++k) {
            float a0 = As[ty * 4 + 0][k], a1 = As[ty * 4 + 1][k];
            float a2 = As[ty * 4 + 2][k], a3 = As[ty * 4 + 3][k];
            float b0 = Bs[tx * 4 + 0][k], b1 = Bs[tx * 4 + 1][k];
            float b2 = Bs[tx * 4 + 2][k], b3 = Bs[tx * 4 + 3][k];
            acc[0][0] += a0 * b0; acc[0][1] += a0 * b1; acc[0][2] += a0 * b2; acc[0][3] += a0 * b3;
            acc[1][0] += a1 * b0; acc[1][1] += a1 * b1; acc[1][2] += a1 * b2; acc[1][3] += a1 * b3;
            acc[2][0] += a2 * b0; acc[2][1] += a2 * b1; acc[2][2] += a2 * b2; acc[2][3] += a2 * b3;
            acc[3][0] += a3 * b0; acc[3][1] += a3 * b1; acc[3][2] += a3 * b2; acc[3][3] += a3 * b3;
        }
        __syncthreads();
    }

    #pragma unroll
    for (int ii = 0; ii < 4; ++ii) {
        int gr = row0 + ty * 4 + ii;
        if (gr >= M) continue;
        #pragma unroll
        for (int jj = 0; jj < 4; ++jj) {
            int gc = col0 + tx * 4 + jj;
            if (gc < N) {
                float o = acc[ii][jj];
                if (bias) o += bias[gc];
                C[(size_t)gr * N + gc] = o;
            }
        }
    }
}

// --------------------- Flash MFMA attention ------------------------------
// Block = (i-tile of 64, b, n). 4 waves x 16 rows. Loop over 16 j-tiles.
// score[i,j] = qw[i]·k[j] + qr[i]·r[j-i+1023]   (1/8 scale folded into q)
__global__ __launch_bounds__(256) void attn_mfma(const float* __restrict__ qkv, // [T*B,3H]
                                                 const float* __restrict__ r,   // [2T-1,H]
                                                 const float* __restrict__ rwb,
                                                 const float* __restrict__ rrb,
                                                 float* __restrict__ out) {     // [T*B,H]
    __shared__ short Ks[64][64];          // bf16, 16B-chunk XOR swizzled
    __shared__ short Vt[64][64];          // V transposed [d][j], swizzled
    __shared__ short Rs[128][64];         // r window, swizzled
    __shared__ float BDs[4][16][80];      // per-wave BD scratch
    __shared__ short Ps[4][16][72];       // per-wave P (bf16), padded

    const int i0  = blockIdx.x * 64;
    const int b   = blockIdx.y >> 4;
    const int n   = blockIdx.y & 15;
    const int tid = threadIdx.x;
    const int w   = tid >> 6;
    const int lane = tid & 63;
    const int lg  = lane >> 4;       // 0..3
    const int lc  = lane & 15;       // 0..15

    const int QS = 3 * H_DIM;        // qkv row stride
    const int hoff = n * DHEAD;

    // ---- Q fragments (A-layout: lane holds row lc, k = 32*ks + 8*lg + e) ----
    bfrag qw[2], qr[2];
    {
        const int row = i0 + 16 * w + lc;
        const float* qrow = qkv + (size_t)(row * B_DIM + b) * QS + hoff;
        #pragma unroll
        for (int ks = 0; ks < 2; ++ks) {
            const int d0 = ks * 32 + lg * 8;
            float4 qa = *(const float4*)(qrow + d0);
            float4 qb = *(const float4*)(qrow + d0 + 4);
            float4 wa = *(const float4*)(rwb + hoff + d0);
            float4 wb = *(const float4*)(rwb + hoff + d0 + 4);
            float4 ra = *(const float4*)(rrb + hoff + d0);
            float4 rb = *(const float4*)(rrb + hoff + d0 + 4);
            const float sc = 0.125f;
            bfrag fw, fr;
            fw[0] = f2bf((qa.x + wa.x) * sc); fw[1] = f2bf((qa.y + wa.y) * sc);
            fw[2] = f2bf((qa.z + wa.z) * sc); fw[3] = f2bf((qa.w + wa.w) * sc);
            fw[4] = f2bf((qb.x + wb.x) * sc); fw[5] = f2bf((qb.y + wb.y) * sc);
            fw[6] = f2bf((qb.z + wb.z) * sc); fw[7] = f2bf((qb.w + wb.w) * sc);
            fr[0] = f2bf((qa.x + ra.x) * sc); fr[1] = f2bf((qa.y + ra.y) * sc);
            fr[2] = f2bf((qa.z + ra.z) * sc); fr[3] = f2bf((qa.w + ra.w) * sc);
            fr[4] = f2bf((qb.x + rb.x) * sc); fr[5] = f2bf((qb.y + rb.y) * sc);
            fr[6] = f2bf((qb.z + rb.z) * sc); fr[7] = f2bf((qb.w + rb.w) * sc);
            qw[ks] = fw; qr[ks] = fr;
        }
    }

    facc ofr[4];
    #pragma unroll
    for (int d = 0; d < 4; ++d) ofr[d] = (facc){0.f, 0.f, 0.f, 0.f};
    float mrow[4] = {-1e30f, -1e30f, -1e30f, -1e30f};
    float lrow[4] = {0.f, 0.f, 0.f, 0.f};
    const int wbase = 16 * (3 - w);

    for (int jt = 0; jt < 16; ++jt) {
        const int j0 = jt * 64;
        const int l_min = j0 + 960 - i0;   // >= 0

        // ---- stage K (swizzled b128 chunks) ----
        for (int id = tid; id < 512; id += 256) {
            const int j = id >> 3, c = id & 7;
            const float* krow = qkv + (size_t)((j0 + j) * B_DIM + b) * QS + H_DIM + hoff + c * 8;
            float4 a = *(const float4*)krow;
            float4 bb = *(const float4*)(krow + 4);
            bfrag f;
            f[0]=f2bf(a.x); f[1]=f2bf(a.y); f[2]=f2bf(a.z); f[3]=f2bf(a.w);
            f[4]=f2bf(bb.x); f[5]=f2bf(bb.y); f[6]=f2bf(bb.z); f[7]=f2bf(bb.w);
            *(bfrag*)&Ks[j][((c ^ (j & 7)) << 3)] = f;
        }
        // ---- stage r window (128 rows, clamped) ----
        for (int id = tid; id < 1024; id += 256) {
            const int rr = id >> 3, c = id & 7;
            int lg_ = l_min + rr; if (lg_ > 2046) lg_ = 2046;
            const float* rrow = r + (size_t)lg_ * H_DIM + hoff + c * 8;
            float4 a = *(const float4*)rrow;
            float4 bb = *(const float4*)(rrow + 4);
            bfrag f;
            f[0]=f2bf(a.x); f[1]=f2bf(a.y); f[2]=f2bf(a.z); f[3]=f2bf(a.w);
            f[4]=f2bf(bb.x); f[5]=f2bf(bb.y); f[6]=f2bf(bb.z); f[7]=f2bf(bb.w);
            *(bfrag*)&Rs[rr][((c ^ (rr & 7)) << 3)] = f;
        }
        // ---- stage V transposed: Vt[d][j] ----
        {
            const int j = tid & 63;
            const float* vrow = qkv + (size_t)((j0 + j) * B_DIM + b) * QS + 2 * H_DIM + hoff;
            for (int c = tid >> 6; c < 8; c += 4) {
                float4 a = *(const float4*)(vrow + c * 8);
                float4 bb = *(const float4*)(vrow + c * 8 + 4);
                float vv[8] = {a.x, a.y, a.z, a.w, bb.x, bb.y, bb.z, bb.w};
                #pragma unroll
                for (int e = 0; e < 8; ++e) {
                    const int d = c * 8 + e;
                    Vt[d][(((j >> 3) ^ (d & 7)) << 3) | (j & 7)] = f2bf(vv[e]);
                }
            }
        }
        __syncthreads();

        // ---- AC: S = Qw · K^T ----
        facc sfr[4];
        #pragma unroll
        for (int js = 0; js < 4; ++js) {
            sfr[js] = (facc){0.f, 0.f, 0.f, 0.f};
            const int jrow = js * 16 + lc;
            #pragma unroll
            for (int ks = 0; ks < 2; ++ks) {
                const int ch = (ks * 4 + lg) ^ (jrow & 7);
                bfrag bf = *(const bfrag*)&Ks[jrow][ch << 3];
                sfr[js] = __builtin_amdgcn_mfma_f32_16x16x32_bf16(qw[ks], bf, sfr[js], 0, 0, 0);
            }
        }
        // ---- BD: wave-local 16x80 block of Qr · r^T ----
        #pragma unroll
        for (int ls = 0; ls < 5; ++ls) {
            facc bd = (facc){0.f, 0.f, 0.f, 0.f};
            const int rrow = wbase + ls * 16 + lc;
            #pragma unroll
            for (int ks = 0; ks < 2; ++ks) {
                const int ch = (ks * 4 + lg) ^ (rrow & 7);
                bfrag bf = *(const bfrag*)&Rs[rrow][ch << 3];
                bd = __builtin_amdgcn_mfma_f32_16x16x32_bf16(qr[ks], bf, bd, 0, 0, 0);
            }
            #pragma unroll
            for (int rg = 0; rg < 4; ++rg)
                BDs[w][lg * 4 + rg][ls * 16 + lc] = bd[rg];
        }

        // ---- gather BD (rel-shift) + online softmax ----
        float pv[4][4], tmax[4] = {-1e30f, -1e30f, -1e30f, -1e30f};
        #pragma unroll
        for (int js = 0; js < 4; ++js)
            #pragma unroll
            for (int rg = 0; rg < 4; ++rg) {
                const int irow = lg * 4 + rg;
                float v = sfr[js][rg] + BDs[w][irow][js * 16 + lc - irow + 15];
                pv[js][rg] = v;
                tmax[rg] = fmaxf(tmax[rg], v);
            }
        #pragma unroll
        for (int m = 1; m < 16; m <<= 1)
            #pragma unroll
            for (int rg = 0; rg < 4; ++rg)
                tmax[rg] = fmaxf(tmax[rg], __shfl_xor(tmax[rg], m));
        float sf_[4], rsum[4];
        #pragma unroll
        for (int rg = 0; rg < 4; ++rg) {
            float mnew = fmaxf(mrow[rg], tmax[rg]);
            sf_[rg] = __expf(mrow[rg] - mnew);
            mrow[rg] = mnew;
            rsum[rg] = 0.f;
        }
        #pragma unroll
        for (int js = 0; js < 4; ++js)
            #pragma unroll
            for (int rg = 0; rg < 4; ++rg) {
                float p = __expf(pv[js][rg] - mrow[rg]);
                rsum[rg] += p;
                Ps[w][lg * 4 + rg][js * 16 + lc] = f2bf(p);
            }
        #pragma unroll
        for (int m = 1; m < 16; m <<= 1)
            #pragma unroll
            for (int rg = 0; rg < 4; ++rg)
                rsum[rg] += __shfl_xor(rsum[rg], m);
        #pragma unroll
        for (int rg = 0; rg < 4; ++rg)
            lrow[rg] = lrow[rg] * sf_[rg] + rsum[rg];
        #pragma unroll
        for (int d = 0; d < 4; ++d)
            #pragma unroll
            for (int rg = 0; rg < 4; ++rg)
                ofr[d][rg] *= sf_[rg];

        // ---- PV: O += P · V ----
        bfrag pf[2];
        #pragma unroll
        for (int ks = 0; ks < 2; ++ks)
            pf[ks] = *(const bfrag*)&Ps[w][lc][ks * 32 + lg * 8];
        #pragma unroll
        for (int d = 0; d < 4; ++d) {
            #pragma unroll
            for (int ks = 0; ks < 2; ++ks) {
                const int vr = d * 16 + lc;
                const int ch = (ks * 4 + lg) ^ (vr & 7);
                bfrag vf = *(const bfrag*)&Vt[vr][ch << 3];
                ofr[d] = __builtin_amdgcn_mfma_f32_16x16x32_bf16(pf[ks], vf, ofr[d], 0, 0, 0);
            }
        }
        __syncthreads();
    }

    // ---- write O / l ----
    #pragma unroll
    for (int rg = 0; rg < 4; ++rg) {
        const float inv = 1.0f / lrow[rg];
        const int row = i0 + 16 * w + lg * 4 + rg;
        float* orow = out + (size_t)(row * B_DIM + b) * H_DIM + hoff;
        #pragma unroll
        for (int d = 0; d < 4; ++d)
            orow[d * 16 + lc] = ofr[d][rg] * inv;
    }
}

extern "C" void kernel_launch(void* const* d_in, const int* in_sizes, int n_in,
                              void* d_out, int out_size, void* d_ws, size_t ws_size,
                              hipStream_t stream) {
    const float* x          = (const float*)d_in[0];
    const float* pos        = (const float*)d_in[1];
    const float* ln_w       = (const float*)d_in[3];
    const float* ln_b       = (const float*)d_in[4];
    const float* in_proj_w  = (const float*)d_in[5];
    const float* in_proj_b  = (const float*)d_in[6];
    const float* pos_proj_w = (const float*)d_in[7];
    const float* r_w_bias   = (const float*)d_in[8];
    const float* r_r_bias   = (const float*)d_in[9];
    const float* out_proj_w = (const float*)d_in[10];
    const float* out_proj_b = (const float*)d_in[11];
    float* out = (float*)d_out;

    float* qn   = (float*)d_ws;                          // [4096,1024]
    float* qkv  = qn + (size_t)NROWS * H_DIM;            // [4096,3072]
    float* rbuf = qkv + (size_t)NROWS * 3 * H_DIM;       // [2047,1024]
    float* attn_out = qn;                                // reuse qn region

    ln_kernel<<<NROWS, 256, 0, stream>>>(x, ln_w, ln_b, qn);

    gemm_bt<<<dim3(3 * H_DIM / 64, NROWS / 64), 256, 0, stream>>>(
        qn, in_proj_w, in_proj_b, qkv, NROWS, 3 * H_DIM, H_DIM);

    gemm_bt<<<dim3(H_DIM / 64, (LPOS + 63) / 64), 256, 0, stream>>>(
        pos, pos_proj_w, nullptr, rbuf, LPOS, H_DIM, H_DIM);

    attn_mfma<<<dim3(T_DIM / 64, B_DIM * NHEAD), 256, 0, stream>>>(
        qkv, rbuf, r_w_bias, r_r_bias, attn_out);

    gemm_bt<<<dim3(H_DIM / 64, NROWS / 64), 256, 0, stream>>>(
        attn_out, out_proj_w, out_proj_b, out, NROWS, H_DIM, H_DIM);
}

// Round 3
// 252.237 us; speedup vs baseline: 22.6630x; 3.7240x over previous
//
#include <hip/hip_runtime.h>
#include <math.h>

#define T_DIM 1024
#define B_DIM 4
#define H_DIM 1024
#define NHEAD 16
#define DHEAD 64
#define NROWS (T_DIM * B_DIM)   // 4096
#define LPOS  (2 * T_DIM - 1)   // 2047
#define QS    (3 * H_DIM)

typedef __attribute__((ext_vector_type(8))) short bfrag;   // 8 bf16
typedef __attribute__((ext_vector_type(4))) short sh4;
typedef __attribute__((ext_vector_type(4))) float facc;

static __device__ __forceinline__ short f2bf(float f) {
    unsigned u = __builtin_bit_cast(unsigned, f);
    u = (u + 0x7FFFu + ((u >> 16) & 1u)) >> 16;   // RNE
    return (short)u;
}
static __device__ __forceinline__ float bf2f(short s) {
    unsigned u = ((unsigned)(unsigned short)s) << 16;
    return __builtin_bit_cast(float, u);
}

#define GLD16(g, l) __builtin_amdgcn_global_load_lds( \
    (const __attribute__((address_space(1))) void*)(g), \
    (__attribute__((address_space(3))) void*)(l), 16, 0, 0)

// ---------------- f32 -> bf16 convert ----------------
__global__ __launch_bounds__(256) void cvt_kernel(const float* __restrict__ in,
                                                  short* __restrict__ out, int n) {
    int i = (blockIdx.x * 256 + threadIdx.x) * 8;
    if (i >= n) return;
    float4 a = *(const float4*)(in + i);
    float4 b = *(const float4*)(in + i + 4);
    bfrag f;
    f[0] = f2bf(a.x); f[1] = f2bf(a.y); f[2] = f2bf(a.z); f[3] = f2bf(a.w);
    f[4] = f2bf(b.x); f[5] = f2bf(b.y); f[6] = f2bf(b.z); f[7] = f2bf(b.w);
    *(bfrag*)(out + i) = f;
}

// ---------------- LayerNorm: f32 in, bf16 out ----------------
__global__ __launch_bounds__(256) void ln_kernel(const float* __restrict__ x,
                                                 const float* __restrict__ w,
                                                 const float* __restrict__ b,
                                                 short* __restrict__ y) {
    int row = blockIdx.x;
    const float* xr = x + (size_t)row * H_DIM;
    short* yr = y + (size_t)row * H_DIM;
    int tid = threadIdx.x;

    float4 v = reinterpret_cast<const float4*>(xr)[tid];
    float s  = v.x + v.y + v.z + v.w;
    float sq = v.x * v.x + v.y * v.y + v.z * v.z + v.w * v.w;

    #pragma unroll
    for (int m = 32; m; m >>= 1) {
        s  += __shfl_xor(s, m);
        sq += __shfl_xor(sq, m);
    }
    __shared__ float red0[4], red1[4];
    int wave = tid >> 6, lane = tid & 63;
    if (lane == 0) { red0[wave] = s; red1[wave] = sq; }
    __syncthreads();
    float tot   = red0[0] + red0[1] + red0[2] + red0[3];
    float totsq = red1[0] + red1[1] + red1[2] + red1[3];
    float mean = tot * (1.0f / H_DIM);
    float var  = totsq * (1.0f / H_DIM) - mean * mean;
    float rstd = rsqrtf(var + 1e-5f);

    float4 wv = reinterpret_cast<const float4*>(w)[tid];
    float4 bv = reinterpret_cast<const float4*>(b)[tid];
    sh4 o;
    o[0] = f2bf((v.x - mean) * rstd * wv.x + bv.x);
    o[1] = f2bf((v.y - mean) * rstd * wv.y + bv.y);
    o[2] = f2bf((v.z - mean) * rstd * wv.z + bv.z);
    o[3] = f2bf((v.w - mean) * rstd * wv.w + bv.w);
    reinterpret_cast<sh4*>(yr)[tid] = o;
}

// -------- bf16 MFMA GEMM: C[M,N] = A[M,K] @ B[N,K]^T + bias --------
// 128x128 tile, BK=64, 256 threads (4 waves, each a 64x64 quadrant).
// LDS linear dest via global_load_lds; source pre-swizzled chunk^=(row&7);
// ds_read_b128 applies the same XOR (T2; rule #21 both-sides).
template<bool OB>
__global__ __launch_bounds__(256) void gemm_mfma(const short* __restrict__ A,
                                                 const short* __restrict__ B,
                                                 const float* __restrict__ bias,
                                                 void* __restrict__ Cv,
                                                 int M, int N, int K) {
    __shared__ short As[128][64];
    __shared__ short Bs[128][64];
    const int tid = threadIdx.x;
    const int w4 = tid >> 6, l = tid & 63;
    const int lc = l & 15, lg = l >> 4;
    const int wr = w4 >> 1, wc = w4 & 1;
    const int row0 = blockIdx.y * 128, col0 = blockIdx.x * 128;
    const int srow = l >> 3;
    const int schunk = ((l & 7) ^ srow) * 8;   // pre-swizzled source chunk (elems)
    const int Mm1 = M - 1;

    facc acc[4][4];
    #pragma unroll
    for (int i = 0; i < 4; ++i)
        #pragma unroll
        for (int j = 0; j < 4; ++j) acc[i][j] = (facc){0.f, 0.f, 0.f, 0.f};

    for (int k0 = 0; k0 < K; k0 += 64) {
        #pragma unroll
        for (int p = 0; p < 4; ++p) {
            int rA = p * 32 + w4 * 8 + srow;
            int ga = row0 + rA; if (ga > Mm1) ga = Mm1;
            GLD16(A + (size_t)ga * K + k0 + schunk,
                  (char*)As + p * 4096 + w4 * 1024);
            GLD16(B + (size_t)(col0 + rA) * K + k0 + schunk,
                  (char*)Bs + p * 4096 + w4 * 1024);
        }
        __syncthreads();

        bfrag af[4][2], bfr[4][2];
        #pragma unroll
        for (int fr = 0; fr < 4; ++fr) {
            const int ra = wr * 64 + fr * 16 + lc;
            #pragma unroll
            for (int ks = 0; ks < 2; ++ks)
                af[fr][ks] = *(const bfrag*)&As[ra][(((ks * 4 + lg) ^ (ra & 7)) << 3)];
        }
        #pragma unroll
        for (int fc = 0; fc < 4; ++fc) {
            const int rb = wc * 64 + fc * 16 + lc;
            #pragma unroll
            for (int ks = 0; ks < 2; ++ks)
                bfr[fc][ks] = *(const bfrag*)&Bs[rb][(((ks * 4 + lg) ^ (rb & 7)) << 3)];
        }
        #pragma unroll
        for (int fr = 0; fr < 4; ++fr)
            #pragma unroll
            for (int fc = 0; fc < 4; ++fc)
                #pragma unroll
                for (int ks = 0; ks < 2; ++ks)
                    acc[fr][fc] = __builtin_amdgcn_mfma_f32_16x16x32_bf16(
                        af[fr][ks], bfr[fc][ks], acc[fr][fc], 0, 0, 0);
        __syncthreads();
    }

    #pragma unroll
    for (int fc = 0; fc < 4; ++fc) {
        const int gc = col0 + wc * 64 + fc * 16 + lc;
        const float bv = bias ? bias[gc] : 0.f;
        #pragma unroll
        for (int fr = 0; fr < 4; ++fr) {
            #pragma unroll
            for (int rg = 0; rg < 4; ++rg) {
                const int gr = row0 + wr * 64 + fr * 16 + lg * 4 + rg;
                if (gr < M) {
                    float o = acc[fr][fc][rg] + bv;
                    if constexpr (OB) ((short*)Cv)[(size_t)gr * N + gc] = f2bf(o);
                    else              ((float*)Cv)[(size_t)gr * N + gc] = o;
                }
            }
        }
    }
}

// --------------------- Flash MFMA attention (bf16 in/out) -----------------
__global__ __launch_bounds__(256) void attn_mfma(const short* __restrict__ qkv, // [T*B,3H] bf16
                                                 const short* __restrict__ r,   // [2T-1,H] bf16
                                                 const float* __restrict__ rwb,
                                                 const float* __restrict__ rrb,
                                                 short* __restrict__ out) {     // [T*B,H] bf16
    __shared__ short Ks[64][64];
    __shared__ short Vt[64][64];
    __shared__ short Rs[128][64];
    __shared__ float BDs[4][16][80];
    __shared__ short Ps[4][16][72];

    const int i0  = blockIdx.x * 64;
    const int b   = blockIdx.y >> 4;
    const int n   = blockIdx.y & 15;
    const int tid = threadIdx.x;
    const int w   = tid >> 6;
    const int lane = tid & 63;
    const int lg  = lane >> 4;
    const int lc  = lane & 15;
    const int hoff = n * DHEAD;

    bfrag qw[2], qr[2];
    {
        const int row = i0 + 16 * w + lc;
        const short* qrow = qkv + (size_t)(row * B_DIM + b) * QS + hoff;
        #pragma unroll
        for (int ks = 0; ks < 2; ++ks) {
            const int d0 = ks * 32 + lg * 8;
            bfrag qv = *(const bfrag*)(qrow + d0);
            float4 wa = *(const float4*)(rwb + hoff + d0);
            float4 wb = *(const float4*)(rwb + hoff + d0 + 4);
            float4 ra = *(const float4*)(rrb + hoff + d0);
            float4 rb = *(const float4*)(rrb + hoff + d0 + 4);
            const float sc = 0.125f;
            float wf[8] = {wa.x, wa.y, wa.z, wa.w, wb.x, wb.y, wb.z, wb.w};
            float rf[8] = {ra.x, ra.y, ra.z, ra.w, rb.x, rb.y, rb.z, rb.w};
            bfrag fw, fr;
            #pragma unroll
            for (int e = 0; e < 8; ++e) {
                float qf = bf2f(qv[e]);
                fw[e] = f2bf((qf + wf[e]) * sc);
                fr[e] = f2bf((qf + rf[e]) * sc);
            }
            qw[ks] = fw; qr[ks] = fr;
        }
    }

    facc ofr[4];
    #pragma unroll
    for (int d = 0; d < 4; ++d) ofr[d] = (facc){0.f, 0.f, 0.f, 0.f};
    float mrow[4] = {-1e30f, -1e30f, -1e30f, -1e30f};
    float lrow[4] = {0.f, 0.f, 0.f, 0.f};
    const int wbase = 16 * (3 - w);

    for (int jt = 0; jt < 16; ++jt) {
        const int j0 = jt * 64;
        const int l_min = j0 + 960 - i0;

        for (int id = tid; id < 512; id += 256) {
            const int j = id >> 3, c = id & 7;
            bfrag f = *(const bfrag*)(qkv + (size_t)((j0 + j) * B_DIM + b) * QS + H_DIM + hoff + c * 8);
            *(bfrag*)&Ks[j][((c ^ (j & 7)) << 3)] = f;
        }
        for (int id = tid; id < 1024; id += 256) {
            const int rr = id >> 3, c = id & 7;
            int lg_ = l_min + rr; if (lg_ > 2046) lg_ = 2046;
            bfrag f = *(const bfrag*)(r + (size_t)lg_ * H_DIM + hoff + c * 8);
            *(bfrag*)&Rs[rr][((c ^ (rr & 7)) << 3)] = f;
        }
        {
            const int j = tid & 63;
            const short* vrow = qkv + (size_t)((j0 + j) * B_DIM + b) * QS + 2 * H_DIM + hoff;
            for (int c = tid >> 6; c < 8; c += 4) {
                bfrag v8 = *(const bfrag*)(vrow + c * 8);
                #pragma unroll
                for (int e = 0; e < 8; ++e) {
                    const int d = c * 8 + e;
                    Vt[d][(((j >> 3) ^ (d & 7)) << 3) | (j & 7)] = v8[e];
                }
            }
        }
        __syncthreads();

        facc sfr[4];
        #pragma unroll
        for (int js = 0; js < 4; ++js) {
            sfr[js] = (facc){0.f, 0.f, 0.f, 0.f};
            const int jrow = js * 16 + lc;
            #pragma unroll
            for (int ks = 0; ks < 2; ++ks) {
                const int ch = (ks * 4 + lg) ^ (jrow & 7);
                bfrag bf = *(const bfrag*)&Ks[jrow][ch << 3];
                sfr[js] = __builtin_amdgcn_mfma_f32_16x16x32_bf16(qw[ks], bf, sfr[js], 0, 0, 0);
            }
        }
        #pragma unroll
        for (int ls = 0; ls < 5; ++ls) {
            facc bd = (facc){0.f, 0.f, 0.f, 0.f};
            const int rrow = wbase + ls * 16 + lc;
            #pragma unroll
            for (int ks = 0; ks < 2; ++ks) {
                const int ch = (ks * 4 + lg) ^ (rrow & 7);
                bfrag bf = *(const bfrag*)&Rs[rrow][ch << 3];
                bd = __builtin_amdgcn_mfma_f32_16x16x32_bf16(qr[ks], bf, bd, 0, 0, 0);
            }
            #pragma unroll
            for (int rg = 0; rg < 4; ++rg)
                BDs[w][lg * 4 + rg][ls * 16 + lc] = bd[rg];
        }

        float pv[4][4], tmax[4] = {-1e30f, -1e30f, -1e30f, -1e30f};
        #pragma unroll
        for (int js = 0; js < 4; ++js)
            #pragma unroll
            for (int rg = 0; rg < 4; ++rg) {
                const int irow = lg * 4 + rg;
                float v = sfr[js][rg] + BDs[w][irow][js * 16 + lc - irow + 15];
                pv[js][rg] = v;
                tmax[rg] = fmaxf(tmax[rg], v);
            }
        #pragma unroll
        for (int m = 1; m < 16; m <<= 1)
            #pragma unroll
            for (int rg = 0; rg < 4; ++rg)
                tmax[rg] = fmaxf(tmax[rg], __shfl_xor(tmax[rg], m));
        float sf_[4], rsum[4];
        #pragma unroll
        for (int rg = 0; rg < 4; ++rg) {
            float mnew = fmaxf(mrow[rg], tmax[rg]);
            sf_[rg] = __expf(mrow[rg] - mnew);
            mrow[rg] = mnew;
            rsum[rg] = 0.f;
        }
        #pragma unroll
        for (int js = 0; js < 4; ++js)
            #pragma unroll
            for (int rg = 0; rg < 4; ++rg) {
                float p = __expf(pv[js][rg] - mrow[rg]);
                rsum[rg] += p;
                Ps[w][lg * 4 + rg][js * 16 + lc] = f2bf(p);
            }
        #pragma unroll
        for (int m = 1; m < 16; m <<= 1)
            #pragma unroll
            for (int rg = 0; rg < 4; ++rg)
                rsum[rg] += __shfl_xor(rsum[rg], m);
        #pragma unroll
        for (int rg = 0; rg < 4; ++rg)
            lrow[rg] = lrow[rg] * sf_[rg] + rsum[rg];
        #pragma unroll
        for (int d = 0; d < 4; ++d)
            #pragma unroll
            for (int rg = 0; rg < 4; ++rg)
                ofr[d][rg] *= sf_[rg];

        bfrag pf[2];
        #pragma unroll
        for (int ks = 0; ks < 2; ++ks)
            pf[ks] = *(const bfrag*)&Ps[w][lc][ks * 32 + lg * 8];
        #pragma unroll
        for (int d = 0; d < 4; ++d) {
            #pragma unroll
            for (int ks = 0; ks < 2; ++ks) {
                const int vr = d * 16 + lc;
                const int ch = (ks * 4 + lg) ^ (vr & 7);
                bfrag vf = *(const bfrag*)&Vt[vr][ch << 3];
                ofr[d] = __builtin_amdgcn_mfma_f32_16x16x32_bf16(pf[ks], vf, ofr[d], 0, 0, 0);
            }
        }
        __syncthreads();
    }

    #pragma unroll
    for (int rg = 0; rg < 4; ++rg) {
        const float inv = 1.0f / lrow[rg];
        const int row = i0 + 16 * w + lg * 4 + rg;
        short* orow = out + (size_t)(row * B_DIM + b) * H_DIM + hoff;
        #pragma unroll
        for (int d = 0; d < 4; ++d)
            orow[d * 16 + lc] = f2bf(ofr[d][rg] * inv);
    }
}

extern "C" void kernel_launch(void* const* d_in, const int* in_sizes, int n_in,
                              void* d_out, int out_size, void* d_ws, size_t ws_size,
                              hipStream_t stream) {
    const float* x          = (const float*)d_in[0];
    const float* pos        = (const float*)d_in[1];
    const float* ln_w       = (const float*)d_in[3];
    const float* ln_b       = (const float*)d_in[4];
    const float* in_proj_w  = (const float*)d_in[5];
    const float* in_proj_b  = (const float*)d_in[6];
    const float* pos_proj_w = (const float*)d_in[7];
    const float* r_w_bias   = (const float*)d_in[8];
    const float* r_r_bias   = (const float*)d_in[9];
    const float* out_proj_w = (const float*)d_in[10];
    const float* out_proj_b = (const float*)d_in[11];
    float* out = (float*)d_out;

    short* qn   = (short*)d_ws;                      // [4096,1024]  (reused as attn_out)
    short* qkv  = qn + (size_t)NROWS * H_DIM;        // [4096,3072]
    short* rbuf = qkv + (size_t)NROWS * QS;          // [2047,1024] (pad to 2048 rows)
    short* wi   = rbuf + (size_t)2048 * H_DIM;       // in_proj_w bf16
    short* wp   = wi + (size_t)QS * H_DIM;           // pos_proj_w bf16
    short* wo   = wp + (size_t)H_DIM * H_DIM;        // out_proj_w bf16
    short* posb = wo + (size_t)H_DIM * H_DIM;        // pos bf16

    const int n_pos = LPOS * H_DIM;
    cvt_kernel<<<(n_pos + 2047) / 2048, 256, 0, stream>>>(pos, posb, n_pos);
    cvt_kernel<<<(QS * H_DIM + 2047) / 2048, 256, 0, stream>>>(in_proj_w, wi, QS * H_DIM);
    cvt_kernel<<<(H_DIM * H_DIM + 2047) / 2048, 256, 0, stream>>>(pos_proj_w, wp, H_DIM * H_DIM);
    cvt_kernel<<<(H_DIM * H_DIM + 2047) / 2048, 256, 0, stream>>>(out_proj_w, wo, H_DIM * H_DIM);

    ln_kernel<<<NROWS, 256, 0, stream>>>(x, ln_w, ln_b, qn);

    gemm_mfma<true><<<dim3(QS / 128, NROWS / 128), 256, 0, stream>>>(
        qn, wi, in_proj_b, qkv, NROWS, QS, H_DIM);

    gemm_mfma<true><<<dim3(H_DIM / 128, (LPOS + 127) / 128), 256, 0, stream>>>(
        posb, wp, nullptr, rbuf, LPOS, H_DIM, H_DIM);

    attn_mfma<<<dim3(T_DIM / 64, B_DIM * NHEAD), 256, 0, stream>>>(
        qkv, rbuf, r_w_bias, r_r_bias, qn);

    gemm_mfma<false><<<dim3(H_DIM / 128, NROWS / 128), 256, 0, stream>>>(
        qn, wo, out_proj_b, out, NROWS, H_DIM, H_DIM);
}

// Round 7
// 222.428 us; speedup vs baseline: 25.7001x; 1.1340x over previous
//
#include <hip/hip_runtime.h>
#include <math.h>

#define T_DIM 1024
#define B_DIM 4
#define H_DIM 1024
#define NHEAD 16
#define DHEAD 64
#define NROWS (T_DIM * B_DIM)   // 4096
#define LPOS  (2 * T_DIM - 1)   // 2047
#define QS    (3 * H_DIM)

typedef __attribute__((ext_vector_type(8))) short bfrag;   // 8 bf16
typedef __attribute__((ext_vector_type(4))) short sh4;
typedef __attribute__((ext_vector_type(4))) float facc;

static __device__ __forceinline__ short f2bf(float f) {
    unsigned u = __builtin_bit_cast(unsigned, f);
    u = (u + 0x7FFFu + ((u >> 16) & 1u)) >> 16;   // RNE
    return (short)u;
}
static __device__ __forceinline__ float bf2f(short s) {
    unsigned u = ((unsigned)(unsigned short)s) << 16;
    return __builtin_bit_cast(float, u);
}

#define GLD16(g, l) __builtin_amdgcn_global_load_lds( \
    (const __attribute__((address_space(1))) void*)(g), \
    (__attribute__((address_space(3))) void*)(l), 16, 0, 0)

// ---------------- f32 -> bf16 convert ----------------
__global__ __launch_bounds__(256) void cvt_kernel(const float* __restrict__ in,
                                                  short* __restrict__ out, int n) {
    int i = (blockIdx.x * 256 + threadIdx.x) * 8;
    if (i >= n) return;
    float4 a = *(const float4*)(in + i);
    float4 b = *(const float4*)(in + i + 4);
    bfrag f;
    f[0] = f2bf(a.x); f[1] = f2bf(a.y); f[2] = f2bf(a.z); f[3] = f2bf(a.w);
    f[4] = f2bf(b.x); f[5] = f2bf(b.y); f[6] = f2bf(b.z); f[7] = f2bf(b.w);
    *(bfrag*)(out + i) = f;
}

// ---------------- LayerNorm: f32 in, bf16 out ----------------
__global__ __launch_bounds__(256) void ln_kernel(const float* __restrict__ x,
                                                 const float* __restrict__ w,
                                                 const float* __restrict__ b,
                                                 short* __restrict__ y) {
    int row = blockIdx.x;
    const float* xr = x + (size_t)row * H_DIM;
    short* yr = y + (size_t)row * H_DIM;
    int tid = threadIdx.x;

    float4 v = reinterpret_cast<const float4*>(xr)[tid];
    float s  = v.x + v.y + v.z + v.w;
    float sq = v.x * v.x + v.y * v.y + v.z * v.z + v.w * v.w;

    #pragma unroll
    for (int m = 32; m; m >>= 1) {
        s  += __shfl_xor(s, m);
        sq += __shfl_xor(sq, m);
    }
    __shared__ float red0[4], red1[4];
    int wave = tid >> 6, lane = tid & 63;
    if (lane == 0) { red0[wave] = s; red1[wave] = sq; }
    __syncthreads();
    float tot   = red0[0] + red0[1] + red0[2] + red0[3];
    float totsq = red1[0] + red1[1] + red1[2] + red1[3];
    float mean = tot * (1.0f / H_DIM);
    float var  = totsq * (1.0f / H_DIM) - mean * mean;
    float rstd = rsqrtf(var + 1e-5f);

    float4 wv = reinterpret_cast<const float4*>(w)[tid];
    float4 bv = reinterpret_cast<const float4*>(b)[tid];
    sh4 o;
    o[0] = f2bf((v.x - mean) * rstd * wv.x + bv.x);
    o[1] = f2bf((v.y - mean) * rstd * wv.y + bv.y);
    o[2] = f2bf((v.z - mean) * rstd * wv.z + bv.z);
    o[3] = f2bf((v.w - mean) * rstd * wv.w + bv.w);
    reinterpret_cast<sh4*>(yr)[tid] = o;
}

// -------- bf16 MFMA GEMM: C[M,N] = A[M,K] @ B[N,K]^T + bias --------
// MODE 0: f32 out. MODE 1: bf16 out. MODE 2: bf16 out + transposed side-write
// of columns >= 2H into vT[b][hd][t] (b = gr&3 == rg, t = gr>>2).
template<int MODE>
__global__ __launch_bounds__(256) void gemm_mfma(const short* __restrict__ A,
                                                 const short* __restrict__ B,
                                                 const float* __restrict__ bias,
                                                 void* __restrict__ Cv,
                                                 short* __restrict__ vT,
                                                 int M, int N, int K) {
    __shared__ short As[128][64];
    __shared__ short Bs[128][64];
    const int tid = threadIdx.x;
    const int w4 = tid >> 6, l = tid & 63;
    const int lc = l & 15, lg = l >> 4;
    const int wr = w4 >> 1, wc = w4 & 1;
    const int row0 = blockIdx.y * 128, col0 = blockIdx.x * 128;
    const int srow = l >> 3;
    const int schunk = ((l & 7) ^ srow) * 8;
    const int Mm1 = M - 1;

    facc acc[4][4];
    #pragma unroll
    for (int i = 0; i < 4; ++i)
        #pragma unroll
        for (int j = 0; j < 4; ++j) acc[i][j] = (facc){0.f, 0.f, 0.f, 0.f};

    for (int k0 = 0; k0 < K; k0 += 64) {
        #pragma unroll
        for (int p = 0; p < 4; ++p) {
            int rA = p * 32 + w4 * 8 + srow;
            int ga = row0 + rA; if (ga > Mm1) ga = Mm1;
            GLD16(A + (size_t)ga * K + k0 + schunk,
                  (char*)As + p * 4096 + w4 * 1024);
            GLD16(B + (size_t)(col0 + rA) * K + k0 + schunk,
                  (char*)Bs + p * 4096 + w4 * 1024);
        }
        __syncthreads();

        bfrag af[4][2], bfr[4][2];
        #pragma unroll
        for (int fr = 0; fr < 4; ++fr) {
            const int ra = wr * 64 + fr * 16 + lc;
            #pragma unroll
            for (int ks = 0; ks < 2; ++ks)
                af[fr][ks] = *(const bfrag*)&As[ra][(((ks * 4 + lg) ^ (ra & 7)) << 3)];
        }
        #pragma unroll
        for (int fc = 0; fc < 4; ++fc) {
            const int rb = wc * 64 + fc * 16 + lc;
            #pragma unroll
            for (int ks = 0; ks < 2; ++ks)
                bfr[fc][ks] = *(const bfrag*)&Bs[rb][(((ks * 4 + lg) ^ (rb & 7)) << 3)];
        }
        #pragma unroll
        for (int fr = 0; fr < 4; ++fr)
            #pragma unroll
            for (int fc = 0; fc < 4; ++fc)
                #pragma unroll
                for (int ks = 0; ks < 2; ++ks)
                    acc[fr][fc] = __builtin_amdgcn_mfma_f32_16x16x32_bf16(
                        af[fr][ks], bfr[fc][ks], acc[fr][fc], 0, 0, 0);
        __syncthreads();
    }

    #pragma unroll
    for (int fc = 0; fc < 4; ++fc) {
        const int gc = col0 + wc * 64 + fc * 16 + lc;
        const float bv = bias ? bias[gc] : 0.f;
        #pragma unroll
        for (int fr = 0; fr < 4; ++fr) {
            #pragma unroll
            for (int rg = 0; rg < 4; ++rg) {
                const int gr = row0 + wr * 64 + fr * 16 + lg * 4 + rg;
                if (gr < M) {
                    float o = acc[fr][fc][rg] + bv;
                    if constexpr (MODE == 0) {
                        ((float*)Cv)[(size_t)gr * N + gc] = o;
                    } else {
                        short ob = f2bf(o);
                        ((short*)Cv)[(size_t)gr * N + gc] = ob;
                        if constexpr (MODE == 2) {
                            if (gc >= 2 * H_DIM) {
                                const int t = gr >> 2, bb = gr & 3;   // bb == rg
                                vT[(((size_t)(bb * H_DIM + (gc - 2 * H_DIM))) << 10) + t] = ob;
                            }
                        }
                    }
                }
            }
        }
    }
}

// --------------------- Flash MFMA attention (bf16 in/out) -----------------
// score[i,j] = qw[i]·k[j] + qr[i]·r[j-i+1023]  (1/8 folded into q)
// Staging (HW-verified in r5 by error-equality): GLD16 K/R/Vt with
// pre-swizzled per-lane global source (rule #21), V pre-transposed in global.
// Rel-shift gather: round-2/3-verified BDs LDS round-trip, now bf16.
__global__ __launch_bounds__(256) void attn_mfma(const short* __restrict__ qkv,
                                                 const short* __restrict__ r,
                                                 const short* __restrict__ vt,
                                                 const float* __restrict__ rwb,
                                                 const float* __restrict__ rrb,
                                                 short* __restrict__ out) {
    __shared__ short Ks[64][64];
    __shared__ short Vt[64][64];
    __shared__ short Rs[128][64];
    __shared__ short BDs[4][16][80];   // bf16 (was f32): 10.25 KB
    __shared__ short Ps[4][16][72];

    const int i0  = blockIdx.x * 64;
    const int b   = blockIdx.y >> 4;
    const int n   = blockIdx.y & 15;
    const int tid = threadIdx.x;
    const int w   = tid >> 6;
    const int l   = tid & 63;
    const int lg  = l >> 4;
    const int lc  = l & 15;
    const int hoff = n * DHEAD;

    // staging source decode (per lane)
    const int srow8 = l >> 3;                        // row within 8-row chunk
    const int sc8   = ((l & 7) ^ srow8) * 8;         // inverse-swizzled col chunk

    // ---- Q fragments ----
    bfrag qw[2], qr[2];
    {
        const int row = i0 + 16 * w + lc;
        const short* qrow = qkv + (size_t)(row * B_DIM + b) * QS + hoff;
        #pragma unroll
        for (int ks = 0; ks < 2; ++ks) {
            const int d0 = ks * 32 + lg * 8;
            bfrag qv = *(const bfrag*)(qrow + d0);
            float4 wa = *(const float4*)(rwb + hoff + d0);
            float4 wb = *(const float4*)(rwb + hoff + d0 + 4);
            float4 ra = *(const float4*)(rrb + hoff + d0);
            float4 rb = *(const float4*)(rrb + hoff + d0 + 4);
            const float sc = 0.125f;
            float wf[8] = {wa.x, wa.y, wa.z, wa.w, wb.x, wb.y, wb.z, wb.w};
            float rf[8] = {ra.x, ra.y, ra.z, ra.w, rb.x, rb.y, rb.z, rb.w};
            bfrag fw, fr;
            #pragma unroll
            for (int e = 0; e < 8; ++e) {
                float qf = bf2f(qv[e]);
                fw[e] = f2bf((qf + wf[e]) * sc);
                fr[e] = f2bf((qf + rf[e]) * sc);
            }
            qw[ks] = fw; qr[ks] = fr;
        }
    }

    facc ofr[4];
    #pragma unroll
    for (int d = 0; d < 4; ++d) ofr[d] = (facc){0.f, 0.f, 0.f, 0.f};
    float mrow[4] = {-1e30f, -1e30f, -1e30f, -1e30f};
    float lrow[4] = {0.f, 0.f, 0.f, 0.f};
    const int wbase = 16 * (3 - w);

    for (int jt = 0; jt < 16; ++jt) {
        const int j0 = jt * 64;
        const int l_min = j0 + 960 - i0;   // in [0, 1920]

        // ---- stage K (2 chunks), R (4), Vt (2) via global_load_lds ----
        #pragma unroll
        for (int p = 0; p < 2; ++p) {
            const int c8 = w * 2 + p;
            const int j = c8 * 8 + srow8;
            GLD16(qkv + (size_t)((j0 + j) * B_DIM + b) * QS + H_DIM + hoff + sc8,
                  (char*)Ks + c8 * 1024);
        }
        #pragma unroll
        for (int p = 0; p < 4; ++p) {
            const int c16 = w * 4 + p;
            int lrw = l_min + c16 * 8 + srow8; if (lrw > 2046) lrw = 2046;
            GLD16(r + (size_t)lrw * H_DIM + hoff + sc8,
                  (char*)Rs + c16 * 1024);
        }
        #pragma unroll
        for (int p = 0; p < 2; ++p) {
            const int c8 = w * 2 + p;
            const int dd = c8 * 8 + srow8;
            GLD16(vt + (((size_t)(b * H_DIM + hoff + dd)) << 10) + j0 + sc8,
                  (char*)Vt + c8 * 1024);
        }
        __syncthreads();

        // ---- AC: S = Qw · K^T ----
        __builtin_amdgcn_s_setprio(1);
        facc sfr[4];
        #pragma unroll
        for (int js = 0; js < 4; ++js) {
            sfr[js] = (facc){0.f, 0.f, 0.f, 0.f};
            const int jrow = js * 16 + lc;
            #pragma unroll
            for (int ks = 0; ks < 2; ++ks) {
                const int ch = (ks * 4 + lg) ^ (jrow & 7);
                bfrag bf = *(const bfrag*)&Ks[jrow][ch << 3];
                sfr[js] = __builtin_amdgcn_mfma_f32_16x16x32_bf16(qw[ks], bf, sfr[js], 0, 0, 0);
            }
        }
        // ---- BD: wave-local 16x80 block of Qr · r^T -> BDs (bf16) ----
        #pragma unroll
        for (int ls = 0; ls < 5; ++ls) {
            facc bd = (facc){0.f, 0.f, 0.f, 0.f};
            const int rrow = wbase + ls * 16 + lc;
            #pragma unroll
            for (int ks = 0; ks < 2; ++ks) {
                const int ch = (ks * 4 + lg) ^ (rrow & 7);
                bfrag bf = *(const bfrag*)&Rs[rrow][ch << 3];
                bd = __builtin_amdgcn_mfma_f32_16x16x32_bf16(qr[ks], bf, bd, 0, 0, 0);
            }
            #pragma unroll
            for (int rg = 0; rg < 4; ++rg)
                BDs[w][lg * 4 + rg][ls * 16 + lc] = f2bf(bd[rg]);
        }
        __builtin_amdgcn_s_setprio(0);

        // ---- rel-shift gather (round-2/3-verified indexing) + softmax ----
        float pv[4][4], tmax[4] = {-1e30f, -1e30f, -1e30f, -1e30f};
        #pragma unroll
        for (int js = 0; js < 4; ++js)
            #pragma unroll
            for (int rg = 0; rg < 4; ++rg) {
                const int irow = lg * 4 + rg;
                float v = sfr[js][rg] + bf2f(BDs[w][irow][js * 16 + lc - irow + 15]);
                pv[js][rg] = v;
                tmax[rg] = fmaxf(tmax[rg], v);
            }
        #pragma unroll
        for (int m = 1; m < 16; m <<= 1)
            #pragma unroll
            for (int rg = 0; rg < 4; ++rg)
                tmax[rg] = fmaxf(tmax[rg], __shfl_xor(tmax[rg], m));
        float sf_[4], rsum[4];
        #pragma unroll
        for (int rg = 0; rg < 4; ++rg) {
            float mnew = fmaxf(mrow[rg], tmax[rg]);
            sf_[rg] = __expf(mrow[rg] - mnew);
            mrow[rg] = mnew;
            rsum[rg] = 0.f;
        }
        #pragma unroll
        for (int js = 0; js < 4; ++js)
            #pragma unroll
            for (int rg = 0; rg < 4; ++rg) {
                float p = __expf(pv[js][rg] - mrow[rg]);
                rsum[rg] += p;
                Ps[w][lg * 4 + rg][js * 16 + lc] = f2bf(p);
            }
        #pragma unroll
        for (int m = 1; m < 16; m <<= 1)
            #pragma unroll
            for (int rg = 0; rg < 4; ++rg)
                rsum[rg] += __shfl_xor(rsum[rg], m);
        #pragma unroll
        for (int rg = 0; rg < 4; ++rg)
            lrow[rg] = lrow[rg] * sf_[rg] + rsum[rg];
        #pragma unroll
        for (int d = 0; d < 4; ++d)
            #pragma unroll
            for (int rg = 0; rg < 4; ++rg)
                ofr[d][rg] *= sf_[rg];

        // ---- PV: O += P · V ----
        bfrag pf[2];
        #pragma unroll
        for (int ks = 0; ks < 2; ++ks)
            pf[ks] = *(const bfrag*)&Ps[w][lc][ks * 32 + lg * 8];
        __builtin_amdgcn_s_setprio(1);
        #pragma unroll
        for (int d = 0; d < 4; ++d) {
            #pragma unroll
            for (int ks = 0; ks < 2; ++ks) {
                const int vr = d * 16 + lc;
                const int ch = (ks * 4 + lg) ^ (vr & 7);
                bfrag vf = *(const bfrag*)&Vt[vr][ch << 3];
                ofr[d] = __builtin_amdgcn_mfma_f32_16x16x32_bf16(pf[ks], vf, ofr[d], 0, 0, 0);
            }
        }
        __builtin_amdgcn_s_setprio(0);
        __syncthreads();
    }

    // ---- write O ----
    #pragma unroll
    for (int rg = 0; rg < 4; ++rg) {
        const float inv = 1.0f / lrow[rg];
        const int row = i0 + 16 * w + lg * 4 + rg;
        short* orow = out + (size_t)(row * B_DIM + b) * H_DIM + hoff;
        #pragma unroll
        for (int d = 0; d < 4; ++d)
            orow[d * 16 + lc] = f2bf(ofr[d][rg] * inv);
    }
}

extern "C" void kernel_launch(void* const* d_in, const int* in_sizes, int n_in,
                              void* d_out, int out_size, void* d_ws, size_t ws_size,
                              hipStream_t stream) {
    const float* x          = (const float*)d_in[0];
    const float* pos        = (const float*)d_in[1];
    const float* ln_w       = (const float*)d_in[3];
    const float* ln_b       = (const float*)d_in[4];
    const float* in_proj_w  = (const float*)d_in[5];
    const float* in_proj_b  = (const float*)d_in[6];
    const float* pos_proj_w = (const float*)d_in[7];
    const float* r_w_bias   = (const float*)d_in[8];
    const float* r_r_bias   = (const float*)d_in[9];
    const float* out_proj_w = (const float*)d_in[10];
    const float* out_proj_b = (const float*)d_in[11];
    float* out = (float*)d_out;

    short* qn   = (short*)d_ws;                      // [4096,1024] (reused as attn_out)
    short* qkv  = qn + (size_t)NROWS * H_DIM;        // [4096,3072]
    short* rbuf = qkv + (size_t)NROWS * QS;          // [2048,1024]
    short* wi   = rbuf + (size_t)2048 * H_DIM;
    short* wp   = wi + (size_t)QS * H_DIM;
    short* wo   = wp + (size_t)H_DIM * H_DIM;
    short* posb = wo + (size_t)H_DIM * H_DIM;        // [2048,1024]
    short* vT   = posb + (size_t)2048 * H_DIM;       // [4][1024][1024] transposed V

    const int n_pos = LPOS * H_DIM;
    cvt_kernel<<<(n_pos + 2047) / 2048, 256, 0, stream>>>(pos, posb, n_pos);
    cvt_kernel<<<(QS * H_DIM + 2047) / 2048, 256, 0, stream>>>(in_proj_w, wi, QS * H_DIM);
    cvt_kernel<<<(H_DIM * H_DIM + 2047) / 2048, 256, 0, stream>>>(pos_proj_w, wp, H_DIM * H_DIM);
    cvt_kernel<<<(H_DIM * H_DIM + 2047) / 2048, 256, 0, stream>>>(out_proj_w, wo, H_DIM * H_DIM);

    ln_kernel<<<NROWS, 256, 0, stream>>>(x, ln_w, ln_b, qn);

    gemm_mfma<2><<<dim3(QS / 128, NROWS / 128), 256, 0, stream>>>(
        qn, wi, in_proj_b, qkv, vT, NROWS, QS, H_DIM);

    gemm_mfma<1><<<dim3(H_DIM / 128, (LPOS + 127) / 128), 256, 0, stream>>>(
        posb, wp, nullptr, rbuf, nullptr, LPOS, H_DIM, H_DIM);

    attn_mfma<<<dim3(T_DIM / 64, B_DIM * NHEAD), 256, 0, stream>>>(
        qkv, rbuf, vT, r_w_bias, r_r_bias, qn);

    gemm_mfma<0><<<dim3(H_DIM / 128, NROWS / 128), 256, 0, stream>>>(
        qn, wo, out_proj_b, out, nullptr, NROWS, H_DIM, H_DIM);
}